// Round 2
// baseline (561.905 us; speedup 1.0000x reference)
//
#include <hip/hip_runtime.h>
#include <stdint.h>

#define B_   256
#define O_   128
#define D_   128
#define IN_  16384
#define NEGF (-9.0e15f)
#define TINYF 1.1754943508222875e-38f

// ---------------- threefry2x32 (JAX, 20 rounds) ----------------
__device__ __forceinline__ void tf2x32(uint32_t k0, uint32_t k1,
                                       uint32_t x0, uint32_t x1,
                                       uint32_t* o0, uint32_t* o1) {
  uint32_t k2 = k0 ^ k1 ^ 0x1BD11BDAu;
#define TFR(r) { x0 += x1; x1 = (x1 << (r)) | (x1 >> (32 - (r))); x1 ^= x0; }
  x0 += k0; x1 += k1;
  TFR(13) TFR(15) TFR(26) TFR(6)
  x0 += k1; x1 += k2 + 1u;
  TFR(17) TFR(29) TFR(16) TFR(24)
  x0 += k2; x1 += k0 + 2u;
  TFR(13) TFR(15) TFR(26) TFR(6)
  x0 += k0; x1 += k1 + 3u;
  TFR(17) TFR(29) TFR(16) TFR(24)
  x0 += k1; x1 += k2 + 4u;
  TFR(13) TFR(15) TFR(26) TFR(6)
  x0 += k2; x1 += k0 + 5u;
#undef TFR
  *o0 = x0; *o1 = x1;
}

// JAX uniform(minval=tiny,maxval=1) -> gumbel (fp32 semantics)
__device__ __forceinline__ float gumbel_bits(uint32_t bits) {
  float f = __uint_as_float((bits >> 9) | 0x3f800000u) - 1.0f;  // [0,1)
  float u = fmaxf(TINYF, f + TINYF);
  return -logf(-logf(u));
}

// ---------------- Kernel A: M[b][p][o] = <enc[b,p,:], W[o, p*D:(p+1)*D]> ----
// grid = (128 p, 4 b-quarters), 256 threads. fp64 accumulate, fp32 store.
__global__ __launch_bounds__(256) void build_M(
    const float* __restrict__ enc, const float* __restrict__ W,
    float* __restrict__ M) {
  const int p  = blockIdx.x;
  const int b0 = blockIdx.y * 64;
  const int t  = threadIdx.x;

  __shared__ float Ws[128][129];  // Ws[o][d]
  __shared__ float Es[64][129];   // Es[b_local][d]

  // stage W block: 128 rows (o) x 128 (d)
  {
    int o = t >> 1, d0 = (t & 1) * 64;
    const float* src = W + (size_t)o * IN_ + p * D_ + d0;
#pragma unroll
    for (int i = 0; i < 16; i++) {
      float4 v = ((const float4*)src)[i];
      Ws[o][d0 + 4 * i + 0] = v.x; Ws[o][d0 + 4 * i + 1] = v.y;
      Ws[o][d0 + 4 * i + 2] = v.z; Ws[o][d0 + 4 * i + 3] = v.w;
    }
  }
  // stage enc block: 64 rows (b) x 128 (d)
  {
    int bl = t >> 2, d0 = (t & 3) * 32;
    const float* src = enc + ((size_t)(b0 + bl) * O_ + p) * D_ + d0;
#pragma unroll
    for (int i = 0; i < 8; i++) {
      float4 v = ((const float4*)src)[i];
      Es[bl][d0 + 4 * i + 0] = v.x; Es[bl][d0 + 4 * i + 1] = v.y;
      Es[bl][d0 + 4 * i + 2] = v.z; Es[bl][d0 + 4 * i + 3] = v.w;
    }
  }
  __syncthreads();

  const int og = t & 15;   // o = jj*16 + og  (lane-contiguous o -> no LDS conflict)
  const int bg = t >> 4;   // b = b0 + bg*4 + i
  double acc[4][8] = {};

  for (int d = 0; d < D_; d++) {
    float a0 = Es[bg * 4 + 0][d], a1 = Es[bg * 4 + 1][d];
    float a2 = Es[bg * 4 + 2][d], a3 = Es[bg * 4 + 3][d];
#pragma unroll
    for (int jj = 0; jj < 8; jj++) {
      double w = (double)Ws[jj * 16 + og][d];
      acc[0][jj] += (double)a0 * w;
      acc[1][jj] += (double)a1 * w;
      acc[2][jj] += (double)a2 * w;
      acc[3][jj] += (double)a3 * w;
    }
  }
#pragma unroll
  for (int i = 0; i < 4; i++) {
    int b = b0 + bg * 4 + i;
#pragma unroll
    for (int jj = 0; jj < 8; jj++) {
      int o = jj * 16 + og;
      M[((size_t)b * O_ + p) * O_ + o] = (float)acc[i][jj];
    }
  }
}

// ---------------- Kernel B: persistent per-row decode loop ----------------
__global__ __launch_bounds__(256) void decode_loop(
    const float* __restrict__ enc, const float* __restrict__ W,
    const float* __restrict__ bias, const float* __restrict__ M, int use_M,
    float* __restrict__ out_pos, float* __restrict__ out_ls,
    float* __restrict__ out_err) {
  const int b = blockIdx.x;
  const int t = threadIdx.x;

  __shared__ double   Pd[O_];
  __shared__ float    p32s[O_];
  __shared__ float    maskv[O_];
  __shared__ float    encb[D_];
  __shared__ double   dpart[256];
  __shared__ int      cnts[256];
  __shared__ uint32_t key0s[O_], key1s[O_];
  __shared__ int sh_top, sh_pos;

  // per-step keys: partitionable split == fold_in: key_j = tf(key42, (0, j))
  if (t < O_) {
    uint32_t a0, a1;
    tf2x32(0u, 42u, 0u, (uint32_t)t, &a0, &a1);
    key0s[t] = a0; key1s[t] = a1;
    maskv[t] = 1.0f;
  }

  // init P[o]
  {
    int o = t & 127, ph = t >> 7;
    double s = 0.0;
    if (use_M) {
      const float* Mb = M + (size_t)b * O_ * O_;
      for (int p = ph * 64; p < ph * 64 + 64; p++)
        s += (double)Mb[(size_t)p * O_ + o];
    } else {
      const float* er = enc + (size_t)b * IN_ + ph * 8192;
      const float* wr = W + (size_t)o * IN_ + ph * 8192;
      for (int k = 0; k < 8192; k += 4) {
        float4 w4 = *(const float4*)(wr + k);
        float4 e4 = *(const float4*)(er + k);
        s += (double)e4.x * w4.x + (double)e4.y * w4.y +
             (double)e4.z * w4.z + (double)e4.w * w4.w;
      }
    }
    dpart[t] = s;
  }
  __syncthreads();
  if (t < O_) Pd[t] = dpart[t] + dpart[t + O_];

  double ls_sum = 0.0;
  int err_sum = 0;
  __syncthreads();

  for (int j = 0; j < O_; j++) {
    if (t < O_) p32s[t] = (float)Pd[t] + bias[t];
    __syncthreads();

    // stable descending rank of RAW p (argsort(-p), index tie-break)
    {
      int o = t & 127, half = t >> 7;
      float v = p32s[o];
      int base = half * 64, c = 0;
      for (int q = 0; q < 64; q++) {
        float pv = p32s[base + q];
        c += (pv > v) || (pv == v && (base + q) < o);
      }
      cnts[t] = c;
    }
    __syncthreads();
    if (t < O_) {
      int c = cnts[t] + cnts[t + O_];
      if (c == j) sh_top = t;
    }
    __syncthreads();

    // wave 0: gumbel + masked log-softmax + argmax sample
    if (t < 64) {
      uint32_t kj0 = key0s[j], kj1 = key1s[j];
      int o1 = t, o2 = t + 64;
      uint32_t m1 = (uint32_t)(b * O_ + o1);
      uint32_t m2 = (uint32_t)(b * O_ + o2);
      uint32_t w0, w1;
      tf2x32(kj0, kj1, 0u, m1, &w0, &w1);
      uint32_t bits1 = w0 ^ w1;               // partitionable 32-bit draw
      tf2x32(kj0, kj1, 0u, m2, &w0, &w1);
      uint32_t bits2 = w0 ^ w1;
      float g1 = gumbel_bits(bits1), g2 = gumbel_bits(bits2);

      float pmA = (maskv[o1] == 0.0f) ? NEGF : p32s[o1];
      float pmB = (maskv[o2] == 0.0f) ? NEGF : p32s[o2];

      float mx = fmaxf(pmA, pmB);
      for (int d = 1; d < 64; d <<= 1) mx = fmaxf(mx, __shfl_xor(mx, d));
      float shA = pmA - mx, shB = pmB - mx;
      float eA = expf(shA), eB = expf(shB);
      float ss = eA + eB;
      for (int d = 1; d < 64; d <<= 1) ss += __shfl_xor(ss, d);
      float lse = logf(ss);
      float lpA = shA - lse, lpB = shB - lse;
      float yA = lpA + g1, yB = lpB + g2;

      float bv; int bi;
      if (yB > yA) { bv = yB; bi = o2; } else { bv = yA; bi = o1; }
      for (int d = 1; d < 64; d <<= 1) {
        float ov = __shfl_xor(bv, d);
        int   oi = __shfl_xor(bi, d);
        if (ov > bv || (ov == bv && oi < bi)) { bv = ov; bi = oi; }
      }
      int pos = bi;
      float lsel = (pos < 64) ? lpA : lpB;
      lsel = __shfl(lsel, pos & 63);
      if (t == 0) {
        sh_pos = pos;
        ls_sum += (double)lsel;
        err_sum += (maskv[sh_top] == 0.0f) ? 1 : 0;
        maskv[pos] = 0.0f;
        out_pos[(size_t)b * O_ + (O_ - 1 - j)] = (float)pos;
      }
    }
    __syncthreads();
    int pos = sh_pos;

    // score update: P[o] -= M[b][pos][o]
    if (use_M) {
      if (t < O_) Pd[t] -= (double)M[((size_t)b * O_ + pos) * O_ + t];
    } else {
      if (t < 32)
        ((float4*)encb)[t] = ((const float4*)(enc + ((size_t)b * O_ + pos) * D_))[t];
      __syncthreads();
      {
        int o = t >> 1, half = t & 1;
        const float* wrow = W + (size_t)o * IN_ + pos * D_ + half * 64;
        double dsum = 0.0;
#pragma unroll
        for (int q = 0; q < 16; q++) {
          float4 w4 = ((const float4*)wrow)[q];
          int e = half * 64 + q * 4;
          dsum += (double)encb[e + 0] * w4.x + (double)encb[e + 1] * w4.y +
                  (double)encb[e + 2] * w4.z + (double)encb[e + 3] * w4.w;
        }
        dpart[t] = dsum;
      }
      __syncthreads();
      if (t < O_) Pd[t] -= dpart[2 * t] + dpart[2 * t + 1];
    }
    __syncthreads();
  }

  if (t == 0) {
    out_ls[b]  = (float)ls_sum;
    out_err[b] = (float)err_sum;
  }
}

extern "C" void kernel_launch(void* const* d_in, const int* in_sizes, int n_in,
                              void* d_out, int out_size, void* d_ws, size_t ws_size,
                              hipStream_t stream) {
  const float* enc  = (const float*)d_in[0];
  const float* W    = (const float*)d_in[1];
  const float* bias = (const float*)d_in[2];
  float* out     = (float*)d_out;
  float* out_pos = out;                  // [256][128] positions (as f32)
  float* out_ls  = out + B_ * O_;        // [256]
  float* out_err = out + B_ * O_ + B_;   // [256]

  float* M = (float*)d_ws;
  const size_t needM = (size_t)B_ * O_ * O_ * sizeof(float);  // 16.7 MB
  int use_M = (ws_size >= needM) ? 1 : 0;

  if (use_M)
    build_M<<<dim3(O_, 4), 256, 0, stream>>>(enc, W, M);
  decode_loop<<<dim3(B_), 256, 0, stream>>>(enc, W, bias, M, use_M,
                                            out_pos, out_ls, out_err);
}

// Round 3
// 443.707 us; speedup vs baseline: 1.2664x; 1.2664x over previous
//
#include <hip/hip_runtime.h>
#include <stdint.h>

#define B_   256
#define O_   128
#define D_   128
#define IN_  16384
#define NEGF (-9.0e15f)
#define TINYF 1.1754943508222875e-38f

// ---------------- threefry2x32 (JAX partitionable, 20 rounds) ----------------
__device__ __forceinline__ void tf2x32(uint32_t k0, uint32_t k1,
                                       uint32_t x0, uint32_t x1,
                                       uint32_t* o0, uint32_t* o1) {
  uint32_t k2 = k0 ^ k1 ^ 0x1BD11BDAu;
#define TFR(r) { x0 += x1; x1 = (x1 << (r)) | (x1 >> (32 - (r))); x1 ^= x0; }
  x0 += k0; x1 += k1;
  TFR(13) TFR(15) TFR(26) TFR(6)
  x0 += k1; x1 += k2 + 1u;
  TFR(17) TFR(29) TFR(16) TFR(24)
  x0 += k2; x1 += k0 + 2u;
  TFR(13) TFR(15) TFR(26) TFR(6)
  x0 += k0; x1 += k1 + 3u;
  TFR(17) TFR(29) TFR(16) TFR(24)
  x0 += k1; x1 += k2 + 4u;
  TFR(13) TFR(15) TFR(26) TFR(6)
  x0 += k2; x1 += k0 + 5u;
#undef TFR
  *o0 = x0; *o1 = x1;
}

// JAX uniform(tiny,1) -> gumbel, fp32 op-for-op
__device__ __forceinline__ float gumbel_bits(uint32_t bits) {
  float f = __uint_as_float((bits >> 9) | 0x3f800000u) - 1.0f;  // [0,1)
  float u = fmaxf(TINYF, f + TINYF);
  return -logf(-logf(u));
}

// ---------------- Kernel A: M[b][p][o] = <enc[b,p,:], W[o, p*D:(p+1)*D]> ----
// grid = (128 p, 4 b-quarters), 256 threads. fp32 4-way split accumulators.
__global__ __launch_bounds__(256) void build_M(
    const float* __restrict__ enc, const float* __restrict__ W,
    float* __restrict__ M) {
  const int p  = blockIdx.x;
  const int b0 = blockIdx.y * 64;
  const int t  = threadIdx.x;

  __shared__ float Ws[128][129];  // Ws[o][d]
  __shared__ float Es[64][129];   // Es[b_local][d]

  {
    int o = t >> 1, d0 = (t & 1) * 64;
    const float* src = W + (size_t)o * IN_ + p * D_ + d0;
#pragma unroll
    for (int i = 0; i < 16; i++) {
      float4 v = ((const float4*)src)[i];
      Ws[o][d0 + 4 * i + 0] = v.x; Ws[o][d0 + 4 * i + 1] = v.y;
      Ws[o][d0 + 4 * i + 2] = v.z; Ws[o][d0 + 4 * i + 3] = v.w;
    }
  }
  {
    int bl = t >> 2, d0 = (t & 3) * 32;
    const float* src = enc + ((size_t)(b0 + bl) * O_ + p) * D_ + d0;
#pragma unroll
    for (int i = 0; i < 8; i++) {
      float4 v = ((const float4*)src)[i];
      Es[bl][d0 + 4 * i + 0] = v.x; Es[bl][d0 + 4 * i + 1] = v.y;
      Es[bl][d0 + 4 * i + 2] = v.z; Es[bl][d0 + 4 * i + 3] = v.w;
    }
  }
  __syncthreads();

  const int og = t & 15;   // o = jj*16 + og
  const int bg = t >> 4;   // b = b0 + bg*4 + i
  // 4-way d-split fp32 accumulators for precision + ILP
  float acc0[4][8] = {}, acc1[4][8] = {}, acc2[4][8] = {}, acc3[4][8] = {};

  for (int d = 0; d < D_; d += 4) {
    float a0[4], a1[4], a2[4], a3[4];
#pragma unroll
    for (int u = 0; u < 4; u++) {
      a0[u] = Es[bg * 4 + 0][d + u]; a1[u] = Es[bg * 4 + 1][d + u];
      a2[u] = Es[bg * 4 + 2][d + u]; a3[u] = Es[bg * 4 + 3][d + u];
    }
#pragma unroll
    for (int jj = 0; jj < 8; jj++) {
      float w0 = Ws[jj * 16 + og][d + 0];
      float w1 = Ws[jj * 16 + og][d + 1];
      float w2 = Ws[jj * 16 + og][d + 2];
      float w3 = Ws[jj * 16 + og][d + 3];
      acc0[0][jj] += a0[0] * w0; acc1[0][jj] += a0[1] * w1;
      acc2[0][jj] += a0[2] * w2; acc3[0][jj] += a0[3] * w3;
      acc0[1][jj] += a1[0] * w0; acc1[1][jj] += a1[1] * w1;
      acc2[1][jj] += a1[2] * w2; acc3[1][jj] += a1[3] * w3;
      acc0[2][jj] += a2[0] * w0; acc1[2][jj] += a2[1] * w1;
      acc2[2][jj] += a2[2] * w2; acc3[2][jj] += a2[3] * w3;
      acc0[3][jj] += a3[0] * w0; acc1[3][jj] += a3[1] * w1;
      acc2[3][jj] += a3[2] * w2; acc3[3][jj] += a3[3] * w3;
    }
  }
#pragma unroll
  for (int i = 0; i < 4; i++) {
    int b = b0 + bg * 4 + i;
#pragma unroll
    for (int jj = 0; jj < 8; jj++) {
      int o = jj * 16 + og;
      double s = (double)acc0[i][jj] + (double)acc1[i][jj] +
                 (double)acc2[i][jj] + (double)acc3[i][jj];
      M[((size_t)b * O_ + p) * O_ + o] = (float)s;
    }
  }
}

// ---------------- Kernel G: gumbel table g[b][j][o] ----------------
// grid = (128 j, 256 b), 128 threads (o).
__global__ __launch_bounds__(128) void gumbel_fill(float* __restrict__ G) {
  const int j = blockIdx.x, b = blockIdx.y, o = threadIdx.x;
  uint32_t k0, k1, w0, w1;
  tf2x32(0u, 42u, 0u, (uint32_t)j, &k0, &k1);          // fold_in(key42, j)
  uint32_t m = (uint32_t)(b * O_ + o);
  tf2x32(k0, k1, 0u, m, &w0, &w1);
  G[((size_t)b * O_ + j) * O_ + o] = gumbel_bits(w0 ^ w1);
}

// ---------------- Kernel B: persistent per-row decode loop ----------------
// 320 threads: wave0 samples; waves1-4 count ranks; t<128 own P/mask state.
__global__ __launch_bounds__(320) void decode_loop(
    const float* __restrict__ enc, const float* __restrict__ W,
    const float* __restrict__ bias, const float* __restrict__ M,
    const float* __restrict__ G, int use_M, int use_G,
    float* __restrict__ out_pos, float* __restrict__ out_ls,
    float* __restrict__ out_err) {
  const int b = blockIdx.x;
  const int t = threadIdx.x;
  const int lane = t & 63;

  __shared__ float Mlds[O_ * O_];   // 64 KB
  __shared__ float Glds[O_ * O_];   // 64 KB
  __shared__ float p32s[O_], maskv[O_], posb[O_];
  __shared__ int   cnt0[O_], cnt1[O_];
  __shared__ uint32_t key0s[O_], key1s[O_];
  __shared__ int sh_pos, sh_err;

  if (t == 0) sh_err = 0;
  if (t < O_) maskv[t] = 1.0f;

  if (use_M) {
    const float4* src = (const float4*)(M + (size_t)b * O_ * O_);
    for (int i = t; i < O_ * O_ / 4; i += 320) ((float4*)Mlds)[i] = src[i];
  } else {
    // safety fallback: build M[b] in-block (slow, never expected)
    for (int idx = t; idx < O_ * O_; idx += 320) {
      int p = idx >> 7, o = idx & 127;
      const float* er = enc + ((size_t)b * O_ + p) * D_;
      const float* wr = W + (size_t)o * IN_ + p * D_;
      float s = 0.f;
      for (int d = 0; d < D_; d += 4) {
        float4 e4 = *(const float4*)(er + d);
        float4 w4 = *(const float4*)(wr + d);
        s += e4.x * w4.x + e4.y * w4.y + e4.z * w4.z + e4.w * w4.w;
      }
      Mlds[idx] = s;
    }
  }
  if (use_G) {
    const float4* src = (const float4*)(G + (size_t)b * O_ * O_);
    for (int i = t; i < O_ * O_ / 4; i += 320) ((float4*)Glds)[i] = src[i];
  } else if (t < O_) {
    uint32_t a0, a1;
    tf2x32(0u, 42u, 0u, (uint32_t)t, &a0, &a1);
    key0s[t] = a0; key1s[t] = a1;
  }
  __syncthreads();

  double Pd = 0.0, ls_sum = 0.0;
  float biasr = 0.f;
  if (t < O_) {
    double s = 0.0;
    for (int p = 0; p < O_; p++) s += (double)Mlds[p * O_ + t];
    Pd = s;
    biasr = bias[t];
    p32s[t] = (float)Pd + biasr;
  }
  __syncthreads();

  for (int j = 0; j < O_; j++) {
    // ============ phase B: sample (wave0) || rank-count (waves1-4) ==========
    if (t < 64) {
      float p1 = p32s[lane], p2 = p32s[lane + 64];
      float mk1 = maskv[lane], mk2 = maskv[lane + 64];
      float g1, g2;
      if (use_G) {
        g1 = Glds[j * O_ + lane];
        g2 = Glds[j * O_ + 64 + lane];
      } else {
        uint32_t kj0 = key0s[j], kj1 = key1s[j], w0, w1;
        uint32_t m1 = (uint32_t)(b * O_ + lane);
        uint32_t m2 = (uint32_t)(b * O_ + lane + 64);
        tf2x32(kj0, kj1, 0u, m1, &w0, &w1); g1 = gumbel_bits(w0 ^ w1);
        tf2x32(kj0, kj1, 0u, m2, &w0, &w1); g2 = gumbel_bits(w0 ^ w1);
      }
      float pm1 = (mk1 == 0.0f) ? NEGF : p1;
      float pm2 = (mk2 == 0.0f) ? NEGF : p2;
      float mx = fmaxf(pm1, pm2);
      for (int d = 1; d < 64; d <<= 1) mx = fmaxf(mx, __shfl_xor(mx, d));
      float s1 = pm1 - mx, s2 = pm2 - mx;
      float ss = expf(s1) + expf(s2);
      for (int d = 1; d < 64; d <<= 1) ss += __shfl_xor(ss, d);
      float lse = logf(ss);
      float lp1 = s1 - lse, lp2 = s2 - lse;
      float y1 = lp1 + g1, y2 = lp2 + g2;
      float bv; int bi;
      if (y2 > y1) { bv = y2; bi = lane + 64; } else { bv = y1; bi = lane; }
      for (int d = 1; d < 64; d <<= 1) {
        float ov = __shfl_xor(bv, d);
        int   oi = __shfl_xor(bi, d);
        if (ov > bv || (ov == bv && oi < bi)) { bv = ov; bi = oi; }
      }
      float lsel = __shfl((bi < 64) ? lp1 : lp2, bi & 63);
      if (t == 0) { sh_pos = bi; ls_sum += (double)lsel; }
    } else {
      // stable descending rank of RAW p: c[o] = #{q: p_q>p_o || (==, q<o)}
      int idx = t - 64;
      int o = idx & 127, half = idx >> 7;
      int qbase = half << 6;
      float v  = p32s[o];
      float vq = p32s[qbase + lane];
      int c = 0;
#pragma unroll
      for (int q = 0; q < 64; q++) {
        float pv = __shfl(vq, q);
        int qg = qbase + q;
        c += (pv > v || (pv == v && qg < o)) ? 1 : 0;
      }
      if (half) cnt1[o] = c; else cnt0[o] = c;
    }
    __syncthreads();

    // ============ phase A: bookkeeping + incremental P update ==============
    if (t < O_) {
      int c = cnt0[t] + cnt1[t];
      float m = maskv[t];                       // mask BEFORE this step's pick
      if (c == j && m == 0.0f) atomicAdd(&sh_err, 1);
      int pos = sh_pos;
      if (t == pos) { maskv[t] = 0.0f; posb[j] = (float)t; }
      if (j < O_ - 1) {
        Pd -= (double)Mlds[pos * O_ + t];
        p32s[t] = (float)Pd + biasr;
      }
    }
    __syncthreads();
  }

  if (t < O_) out_pos[(size_t)b * O_ + t] = posb[O_ - 1 - t];
  if (t == 0) {
    out_ls[b]  = (float)ls_sum;
    out_err[b] = (float)sh_err;
  }
}

extern "C" void kernel_launch(void* const* d_in, const int* in_sizes, int n_in,
                              void* d_out, int out_size, void* d_ws, size_t ws_size,
                              hipStream_t stream) {
  const float* enc  = (const float*)d_in[0];
  const float* W    = (const float*)d_in[1];
  const float* bias = (const float*)d_in[2];
  float* out     = (float*)d_out;
  float* out_pos = out;                  // [256][128] positions (as f32)
  float* out_ls  = out + B_ * O_;        // [256]
  float* out_err = out + B_ * O_ + B_;   // [256]

  const size_t needM = (size_t)B_ * O_ * O_ * sizeof(float);  // 16.7 MB
  float* M = (float*)d_ws;
  float* G = (float*)d_ws + (size_t)B_ * O_ * O_;
  int use_M = (ws_size >= needM) ? 1 : 0;
  int use_G = (ws_size >= 2 * needM) ? 1 : 0;

  if (use_M) build_M<<<dim3(O_, 4), 256, 0, stream>>>(enc, W, M);
  if (use_G) gumbel_fill<<<dim3(O_, B_), 128, 0, stream>>>(G);
  decode_loop<<<dim3(B_), 320, 0, stream>>>(enc, W, bias, M, G, use_M, use_G,
                                            out_pos, out_ls, out_err);
}

// Round 5
// 365.862 us; speedup vs baseline: 1.5358x; 1.2128x over previous
//
#include <hip/hip_runtime.h>
#include <stdint.h>

#define B_   256
#define O_   128
#define D_   128
#define IN_  16384
#define NEGF (-9.0e15f)
#define TINYF 1.1754943508222875e-38f

// ---------------- threefry2x32 (JAX partitionable, 20 rounds) ----------------
__device__ __forceinline__ void tf2x32(uint32_t k0, uint32_t k1,
                                       uint32_t x0, uint32_t x1,
                                       uint32_t* o0, uint32_t* o1) {
  uint32_t k2 = k0 ^ k1 ^ 0x1BD11BDAu;
#define TFR(r) { x0 += x1; x1 = (x1 << (r)) | (x1 >> (32 - (r))); x1 ^= x0; }
  x0 += k0; x1 += k1;
  TFR(13) TFR(15) TFR(26) TFR(6)
  x0 += k1; x1 += k2 + 1u;
  TFR(17) TFR(29) TFR(16) TFR(24)
  x0 += k2; x1 += k0 + 2u;
  TFR(13) TFR(15) TFR(26) TFR(6)
  x0 += k0; x1 += k1 + 3u;
  TFR(17) TFR(29) TFR(16) TFR(24)
  x0 += k1; x1 += k2 + 4u;
  TFR(13) TFR(15) TFR(26) TFR(6)
  x0 += k2; x1 += k0 + 5u;
#undef TFR
  *o0 = x0; *o1 = x1;
}

__device__ __forceinline__ float gumbel_bits(uint32_t bits) {
  float f = __uint_as_float((bits >> 9) | 0x3f800000u) - 1.0f;  // [0,1)
  float u = fmaxf(TINYF, f + TINYF);
  return -logf(-logf(u));
}

// monotone map fp32 -> uint32 (order-preserving incl. negatives)
__device__ __forceinline__ uint32_t mono32(float x) {
  int b = __float_as_int(x);
  return (uint32_t)b ^ ((uint32_t)(b >> 31) | 0x80000000u);
}

__device__ __forceinline__ float rl_f(float v, int l) {
  return __int_as_float(__builtin_amdgcn_readlane(__float_as_int(v), l));
}
__device__ __forceinline__ double rl_d(double v, int l) {
  long long x = __double_as_longlong(v);
  int lo = __builtin_amdgcn_readlane((int)(x & 0xFFFFFFFFll), l);
  int hi = __builtin_amdgcn_readlane((int)(x >> 32), l);
  return __longlong_as_double(((long long)hi << 32) | (unsigned int)lo);
}

// ---------------- Kernel A: M[b][p][o] = <enc[b,p,:], W[o, p*D:(p+1)*D]> ----
// grid = (128 p, 2 b-halves), 256 threads, 8x8 register tiles.
__global__ __launch_bounds__(256, 1) void build_M(
    const float* __restrict__ enc, const float* __restrict__ W,
    float* __restrict__ M, double* __restrict__ acc_ls,
    int* __restrict__ acc_err) {
  const int p  = blockIdx.x;
  const int b0 = blockIdx.y * 128;
  const int t  = threadIdx.x;
  if (blockIdx.x == 0 && blockIdx.y == 0) { acc_ls[t] = 0.0; acc_err[t] = 0; }

  __shared__ float Ws[128 * 132];  // Ws[o][d], row stride 132
  __shared__ float Es[128 * 132];  // Es[b_local][d]

  // stage: thread t stages one full 512 B row = 32 x float4   (BUGFIX: was 8)
  {
    const float* src = (t < 128)
        ? (W + (size_t)t * IN_ + p * D_)
        : (enc + ((size_t)(b0 + t - 128) * O_ + p) * D_);
    float* dst = (t < 128) ? (Ws + t * 132) : (Es + (t - 128) * 132);
#pragma unroll
    for (int i = 0; i < 32; i++) ((float4*)dst)[i] = ((const float4*)src)[i];
  }
  __syncthreads();

  const int og = t & 15, bg = t >> 4;   // o = og+16*oi, b_local = bg+16*bi
  float acc0[8][8] = {}, acc1[8][8] = {};

  for (int dc = 0; dc < 128; dc += 4) {
    float4 wv[8], ev[8];
#pragma unroll
    for (int oi = 0; oi < 8; oi++)
      wv[oi] = *(const float4*)(Ws + (og + 16 * oi) * 132 + dc);
#pragma unroll
    for (int bi = 0; bi < 8; bi++)
      ev[bi] = *(const float4*)(Es + (bg + 16 * bi) * 132 + dc);
#pragma unroll
    for (int bi = 0; bi < 8; bi++)
#pragma unroll
      for (int oi = 0; oi < 8; oi++) {
        acc0[bi][oi] += ev[bi].x * wv[oi].x;
        acc1[bi][oi] += ev[bi].y * wv[oi].y;
        acc0[bi][oi] += ev[bi].z * wv[oi].z;
        acc1[bi][oi] += ev[bi].w * wv[oi].w;
      }
  }
#pragma unroll
  for (int bi = 0; bi < 8; bi++) {
    int b = b0 + bg + 16 * bi;
#pragma unroll
    for (int oi = 0; oi < 8; oi++) {
      int o = og + 16 * oi;
      M[((size_t)b * O_ + p) * O_ + o] = acc0[bi][oi] + acc1[bi][oi];
    }
  }
}

// ---------------- Kernel S: per-row sampler (wave0) + gumbel producers -------
__global__ __launch_bounds__(256, 1) void sampler(
    const float* __restrict__ M, const float* __restrict__ bias,
    float* __restrict__ out_pos, int* __restrict__ posseq) {
  const int b = blockIdx.x;
  const int t = threadIdx.x;
  const int lane = t & 63;
  const int w = t >> 6;

  __shared__ float Mlds[O_ * O_];   // 64 KB
  __shared__ float Glds[O_ * O_];   // 64 KB
  __shared__ int   flags[O_];

  // stage M[b] cooperatively
  {
    const float4* src = (const float4*)(M + (size_t)b * O_ * O_);
    for (int i = t; i < O_ * O_ / 4; i += 256) ((float4*)Mlds)[i] = src[i];
  }
  if (t < O_) flags[t] = 0;
  __syncthreads();

  if (w > 0) {
    // producer waves: fill gumbel rows round-robin, publish via release store
    for (int r = w - 1; r < O_; r += 3) {
      uint32_t k0j, k1j, w0, w1;
      tf2x32(0u, 42u, 0u, (uint32_t)r, &k0j, &k1j);
      uint32_t m1 = (uint32_t)(b * O_ + lane);
      tf2x32(k0j, k1j, 0u, m1, &w0, &w1);
      float g1 = gumbel_bits(w0 ^ w1);
      tf2x32(k0j, k1j, 0u, m1 + 64u, &w0, &w1);
      float g2 = gumbel_bits(w0 ^ w1);
      Glds[r * O_ + lane] = g1;
      Glds[r * O_ + 64 + lane] = g2;
      if (lane == 0)
        __hip_atomic_store(&flags[r], 1, __ATOMIC_RELEASE,
                           __HIP_MEMORY_SCOPE_WORKGROUP);
    }
    return;
  }

  // ---- wave 0: the serial chain ----
#define WAITROW(r) { int _n = 0; \
    while (__hip_atomic_load(&flags[r], __ATOMIC_ACQUIRE, \
                             __HIP_MEMORY_SCOPE_WORKGROUP) == 0 && \
           _n < (1 << 27)) { _n++; __builtin_amdgcn_s_sleep(1); } }

  double Pd1 = 0.0, Pd2 = 0.0;
  for (int p = 0; p < O_; p++) {
    Pd1 += (double)Mlds[p * O_ + lane];
    Pd2 += (double)Mlds[p * O_ + 64 + lane];
  }
  const float b1f = bias[lane], b2f = bias[lane + 64];
  int mk1 = 0, mk2 = 0;

  float g1c, g2c, g1n, g2n;
  WAITROW(0); g1c = Glds[lane];        g2c = Glds[64 + lane];
  WAITROW(1); g1n = Glds[O_ + lane];   g2n = Glds[O_ + 64 + lane];

  for (int j = 0; j < O_; j++) {
    // exact reference op order: masked scores -> max -> exp-sum -> lse -> lp
    float pm1 = mk1 ? NEGF : ((float)Pd1 + b1f);
    float pm2 = mk2 ? NEGF : ((float)Pd2 + b2f);
    float mx = fmaxf(pm1, pm2);
#pragma unroll
    for (int d = 1; d < 64; d <<= 1) mx = fmaxf(mx, __shfl_xor(mx, d));
    float s1 = pm1 - mx, s2 = pm2 - mx;
    float ss = expf(s1) + expf(s2);
#pragma unroll
    for (int d = 1; d < 64; d <<= 1) ss += __shfl_xor(ss, d);
    float lse = logf(ss);
    float y1 = (s1 - lse) + g1c;
    float y2 = (s2 - lse) + g2c;

    float bv; int bi;
    if (y2 > y1) { bv = y2; bi = lane + 64; } else { bv = y1; bi = lane; }
#pragma unroll
    for (int d = 1; d < 64; d <<= 1) {
      float ov = __shfl_xor(bv, d);
      int   oi = __shfl_xor(bi, d);
      if (ov > bv || (ov == bv && oi < bi)) { bv = ov; bi = oi; }
    }
    int pos = bi;

    if (lane == 0) {
      posseq[b * O_ + j] = pos;
      out_pos[(size_t)b * O_ + (O_ - 1 - j)] = (float)pos;
    }
    mk1 |= (lane == pos);
    mk2 |= (lane + 64 == pos);
    Pd1 -= (double)Mlds[pos * O_ + lane];
    Pd2 -= (double)Mlds[pos * O_ + 64 + lane];

    g1c = g1n; g2c = g2n;
    int r = j + 2;
    if (r < O_) {
      WAITROW(r);
      g1n = Glds[r * O_ + lane];
      g2n = Glds[r * O_ + 64 + lane];
    }
  }
#undef WAITROW
}

// ---------------- Kernel E: rank/err + log-softmax/ls, (b, 8-step chunk) ----
// grid = 256*16 single-wave blocks; zero LDS, zero barriers.
__global__ __launch_bounds__(64) void epilogue(
    const float* __restrict__ M, const float* __restrict__ bias,
    const int* __restrict__ posseq,
    double* __restrict__ acc_ls, int* __restrict__ acc_err) {
  const int bid = blockIdx.x;
  const int b = bid >> 4, jc = bid & 15, j0 = jc * 8;
  const int lane = threadIdx.x;
  const float* Mb = M + (size_t)b * O_ * O_;

  // posseq in regs: lane holds pos[lane], pos[64+lane]
  const int pa = posseq[b * O_ + lane];
  const int pb = posseq[b * O_ + 64 + lane];

  // bit-identical reconstruction of sampler's fp64 score state at j0
  double Pd1 = 0.0, Pd2 = 0.0;
  for (int p = 0; p < O_; p++) {
    Pd1 += (double)Mb[p * O_ + lane];
    Pd2 += (double)Mb[p * O_ + 64 + lane];
  }
  int mk1 = 0, mk2 = 0;
  for (int i = 0; i < j0; i++) {
    int pos = __builtin_amdgcn_readlane(i < 64 ? pa : pb, i & 63);
    mk1 |= (pos == lane);
    mk2 |= (pos == lane + 64);
    Pd1 -= (double)Mb[pos * O_ + lane];
    Pd2 -= (double)Mb[pos * O_ + 64 + lane];
  }
  const float b1f = bias[lane], b2f = bias[lane + 64];

  double ls_acc = 0.0;
  int err_acc = 0;

  for (int j = j0; j < j0 + 8; j++) {
    float p1 = (float)Pd1 + b1f;   // == sampler's unmasked score, bit-identical
    float p2 = (float)Pd2 + b2f;
    // fp64-packed argsort keys: key = mono(p)*128 + (127 - idx); exact in fp64
    double k1 = (double)mono32(p1) * 128.0 + (double)(127 - lane);
    double k2 = (double)mono32(p2) * 128.0 + (double)(63 - lane);
    int c1 = 0, c2 = 0;
#pragma unroll 8
    for (int q = 0; q < 64; q++) {
      double s1 = rl_d(k1, q);
      double s2 = rl_d(k2, q);
      c1 += (s1 > k1) ? 1 : 0;
      c1 += (s2 > k1) ? 1 : 0;
      c2 += (s1 > k2) ? 1 : 0;
      c2 += (s2 > k2) ? 1 : 0;
    }
    // element with rank exactly j; err if already chosen (mask==0)
    unsigned long long t1 = __ballot(c1 == j);
    unsigned long long t2 = __ballot(c2 == j);
    if (t1) err_acc += __builtin_amdgcn_readlane(mk1, __ffsll(t1) - 1);
    else if (t2) err_acc += __builtin_amdgcn_readlane(mk2, __ffsll(t2) - 1);

    // masked log-softmax pieces for ls
    float pm1 = mk1 ? NEGF : p1;
    float pm2 = mk2 ? NEGF : p2;
    float mx = fmaxf(pm1, pm2);
#pragma unroll
    for (int d = 1; d < 64; d <<= 1) mx = fmaxf(mx, __shfl_xor(mx, d));
    float ss = expf(pm1 - mx) + expf(pm2 - mx);
#pragma unroll
    for (int d = 1; d < 64; d <<= 1) ss += __shfl_xor(ss, d);
    float lse = logf(ss);

    int pos = __builtin_amdgcn_readlane(j < 64 ? pa : pb, j & 63);
    float psel = (pos < 64) ? rl_f(p1, pos) : rl_f(p2, pos - 64);
    ls_acc += (double)((psel - mx) - lse);

    // advance state
    mk1 |= (pos == lane);
    mk2 |= (pos == lane + 64);
    Pd1 -= (double)Mb[pos * O_ + lane];
    Pd2 -= (double)Mb[pos * O_ + 64 + lane];
  }
  if (lane == 0) {
    atomicAdd(&acc_ls[b], ls_acc);
    atomicAdd(&acc_err[b], err_acc);
  }
}

// ---------------- Kernel P: pack accumulators to output ----------------
__global__ __launch_bounds__(256) void pack_out(
    const double* __restrict__ acc_ls, const int* __restrict__ acc_err,
    float* __restrict__ out_ls, float* __restrict__ out_err) {
  int t = threadIdx.x;
  out_ls[t]  = (float)acc_ls[t];
  out_err[t] = (float)acc_err[t];
}

extern "C" void kernel_launch(void* const* d_in, const int* in_sizes, int n_in,
                              void* d_out, int out_size, void* d_ws, size_t ws_size,
                              hipStream_t stream) {
  const float* enc  = (const float*)d_in[0];
  const float* W    = (const float*)d_in[1];
  const float* bias = (const float*)d_in[2];
  float* out     = (float*)d_out;
  float* out_pos = out;                  // [256][128] positions (as f32)
  float* out_ls  = out + B_ * O_;        // [256]
  float* out_err = out + B_ * O_ + B_;   // [256]

  char* ws = (char*)d_ws;
  int*    posseq  = (int*)ws;                       // 131072 B
  double* acc_ls  = (double*)(ws + 131072);         // 2048 B
  int*    acc_err = (int*)(ws + 133120);            // 1024 B
  float*  M       = (float*)(ws + 134144);          // 16.7 MB

  build_M<<<dim3(O_, 2), 256, 0, stream>>>(enc, W, M, acc_ls, acc_err);
  sampler<<<dim3(B_), 256, 0, stream>>>(M, bias, out_pos, posseq);
  epilogue<<<dim3(B_ * 16), 64, 0, stream>>>(M, bias, posseq, acc_ls, acc_err);
  pack_out<<<dim3(1), 256, 0, stream>>>(acc_ls, acc_err, out_ls, out_err);
}

// Round 6
// 237.726 us; speedup vs baseline: 2.3637x; 1.5390x over previous
//
#include <hip/hip_runtime.h>
#include <stdint.h>

#define B_   256
#define O_   128
#define D_   128
#define IN_  16384
#define NEGF (-9.0e15f)
#define TINYF 1.1754943508222875e-38f

// ---------------- threefry2x32 (JAX partitionable, 20 rounds) ----------------
__device__ __forceinline__ void tf2x32(uint32_t k0, uint32_t k1,
                                       uint32_t x0, uint32_t x1,
                                       uint32_t* o0, uint32_t* o1) {
  uint32_t k2 = k0 ^ k1 ^ 0x1BD11BDAu;
#define TFR(r) { x0 += x1; x1 = (x1 << (r)) | (x1 >> (32 - (r))); x1 ^= x0; }
  x0 += k0; x1 += k1;
  TFR(13) TFR(15) TFR(26) TFR(6)
  x0 += k1; x1 += k2 + 1u;
  TFR(17) TFR(29) TFR(16) TFR(24)
  x0 += k2; x1 += k0 + 2u;
  TFR(13) TFR(15) TFR(26) TFR(6)
  x0 += k0; x1 += k1 + 3u;
  TFR(17) TFR(29) TFR(16) TFR(24)
  x0 += k1; x1 += k2 + 4u;
  TFR(13) TFR(15) TFR(26) TFR(6)
  x0 += k2; x1 += k0 + 5u;
#undef TFR
  *o0 = x0; *o1 = x1;
}

__device__ __forceinline__ float gumbel_bits(uint32_t bits) {
  float f = __uint_as_float((bits >> 9) | 0x3f800000u) - 1.0f;  // [0,1)
  float u = fmaxf(TINYF, f + TINYF);
  return -logf(-logf(u));
}

// monotone map fp32 -> uint32 (order-preserving incl. negatives)
__device__ __forceinline__ uint32_t mono32(float x) {
  int b = __float_as_int(x);
  return (uint32_t)b ^ ((uint32_t)(b >> 31) | 0x80000000u);
}

__device__ __forceinline__ float rl_f(float v, int l) {
  return __int_as_float(__builtin_amdgcn_readlane(__float_as_int(v), l));
}
__device__ __forceinline__ uint32_t rl_u(uint32_t v, int l) {
  return (uint32_t)__builtin_amdgcn_readlane((int)v, l);
}
__device__ __forceinline__ uint64_t rl_u64(uint64_t v, int l) {
  uint32_t lo = (uint32_t)__builtin_amdgcn_readlane((int)(uint32_t)v, l);
  uint32_t hi = (uint32_t)__builtin_amdgcn_readlane((int)(uint32_t)(v >> 32), l);
  return ((uint64_t)hi << 32) | lo;
}

// DPP butterfly (VALU, ~4cyc/op) — xor1, xor2, xor4, xor8 within each row of 16.
// Sum tree association matches the old __shfl_xor butterfly => bit-identical ss.
#define DPPF(x, ctrl) __int_as_float(__builtin_amdgcn_mov_dpp( \
    __float_as_int(x), (ctrl), 0xf, 0xf, true))
#define DPPU(x, ctrl) ((uint32_t)__builtin_amdgcn_mov_dpp( \
    (int)(x), (ctrl), 0xf, 0xf, true))

__device__ __forceinline__ float wredmaxf(float x) {
  x = fmaxf(x, DPPF(x, 0xB1));    // quad_perm [1,0,3,2]  (xor1)
  x = fmaxf(x, DPPF(x, 0x4E));    // quad_perm [2,3,0,1]  (xor2)
  x = fmaxf(x, DPPF(x, 0x141));   // row_half_mirror      (xor4)
  x = fmaxf(x, DPPF(x, 0x140));   // row_mirror           (xor8)
  float a = rl_f(x, 0), b = rl_f(x, 16), c = rl_f(x, 32), d = rl_f(x, 48);
  return fmaxf(fmaxf(a, b), fmaxf(c, d));
}
__device__ __forceinline__ float wredsumf(float x) {
  x = x + DPPF(x, 0xB1);
  x = x + DPPF(x, 0x4E);
  x = x + DPPF(x, 0x141);
  x = x + DPPF(x, 0x140);
  float a = rl_f(x, 0), b = rl_f(x, 16), c = rl_f(x, 32), d = rl_f(x, 48);
  return (a + b) + (c + d);       // same association as xor16,xor32 butterfly
}
__device__ __forceinline__ uint32_t wredmaxu(uint32_t x) {
  uint32_t y;
  y = DPPU(x, 0xB1);  x = x > y ? x : y;
  y = DPPU(x, 0x4E);  x = x > y ? x : y;
  y = DPPU(x, 0x141); x = x > y ? x : y;
  y = DPPU(x, 0x140); x = x > y ? x : y;
  uint32_t a = rl_u(x, 0), b = rl_u(x, 16), c = rl_u(x, 32), d = rl_u(x, 48);
  a = a > b ? a : b; c = c > d ? c : d;
  return a > c ? a : c;
}

// ---------------- Kernel A: M[b][p][o] = <enc[b,p,:], W[o, p*D:(p+1)*D]> ----
__global__ __launch_bounds__(256, 1) void build_M(
    const float* __restrict__ enc, const float* __restrict__ W,
    float* __restrict__ M, int* __restrict__ acc_err) {
  const int p  = blockIdx.x;
  const int b0 = blockIdx.y * 128;
  const int t  = threadIdx.x;
  if (blockIdx.x == 0 && blockIdx.y == 0) acc_err[t] = 0;

  __shared__ float Ws[128 * 132];  // Ws[o][d], row stride 132
  __shared__ float Es[128 * 132];  // Es[b_local][d]

  {
    const float* src = (t < 128)
        ? (W + (size_t)t * IN_ + p * D_)
        : (enc + ((size_t)(b0 + t - 128) * O_ + p) * D_);
    float* dst = (t < 128) ? (Ws + t * 132) : (Es + (t - 128) * 132);
#pragma unroll
    for (int i = 0; i < 32; i++) ((float4*)dst)[i] = ((const float4*)src)[i];
  }
  __syncthreads();

  const int og = t & 15, bg = t >> 4;   // o = og+16*oi, b_local = bg+16*bi
  float acc0[8][8] = {}, acc1[8][8] = {};

  for (int dc = 0; dc < 128; dc += 4) {
    float4 wv[8], ev[8];
#pragma unroll
    for (int oi = 0; oi < 8; oi++)
      wv[oi] = *(const float4*)(Ws + (og + 16 * oi) * 132 + dc);
#pragma unroll
    for (int bi = 0; bi < 8; bi++)
      ev[bi] = *(const float4*)(Es + (bg + 16 * bi) * 132 + dc);
#pragma unroll
    for (int bi = 0; bi < 8; bi++)
#pragma unroll
      for (int oi = 0; oi < 8; oi++) {
        acc0[bi][oi] += ev[bi].x * wv[oi].x;
        acc1[bi][oi] += ev[bi].y * wv[oi].y;
        acc0[bi][oi] += ev[bi].z * wv[oi].z;
        acc1[bi][oi] += ev[bi].w * wv[oi].w;
      }
  }
#pragma unroll
  for (int bi = 0; bi < 8; bi++) {
    int b = b0 + bg + 16 * bi;
#pragma unroll
    for (int oi = 0; oi < 8; oi++) {
      int o = og + 16 * oi;
      M[((size_t)b * O_ + p) * O_ + o] = acc0[bi][oi] + acc1[bi][oi];
    }
  }
}

// ---------------- Kernel S: per-row sampler + gumbel producers ----------------
__global__ __launch_bounds__(256, 1) void sampler(
    const float* __restrict__ M, const float* __restrict__ bias,
    float* __restrict__ out_pos, float* __restrict__ out_ls,
    int* __restrict__ posseq, double* __restrict__ snapPd,
    unsigned long long* __restrict__ snapMk, int snap) {
  const int b = blockIdx.x;
  const int t = threadIdx.x;
  const int lane = t & 63;
  const int w = t >> 6;

  __shared__ float Mlds[O_ * O_];   // 64 KB
  __shared__ float Glds[O_ * O_];   // 64 KB
  __shared__ int   flags[O_];

  {
    const float4* src = (const float4*)(M + (size_t)b * O_ * O_);
    for (int i = t; i < O_ * O_ / 4; i += 256) ((float4*)Mlds)[i] = src[i];
  }
  if (t < O_) flags[t] = 0;
  __syncthreads();

  if (w > 0) {
    for (int r = w - 1; r < O_; r += 3) {
      uint32_t k0j, k1j, w0, w1;
      tf2x32(0u, 42u, 0u, (uint32_t)r, &k0j, &k1j);
      uint32_t m1 = (uint32_t)(b * O_ + lane);
      tf2x32(k0j, k1j, 0u, m1, &w0, &w1);
      float g1 = gumbel_bits(w0 ^ w1);
      tf2x32(k0j, k1j, 0u, m1 + 64u, &w0, &w1);
      float g2 = gumbel_bits(w0 ^ w1);
      Glds[r * O_ + lane] = g1;
      Glds[r * O_ + 64 + lane] = g2;
      if (lane == 0)
        __hip_atomic_store(&flags[r], 1, __ATOMIC_RELEASE,
                           __HIP_MEMORY_SCOPE_WORKGROUP);
    }
    return;
  }

  // ---- wave 0: serial chain ----
#define WAITROW(r) { int _n = 0; \
    while (__hip_atomic_load(&flags[r], __ATOMIC_ACQUIRE, \
                             __HIP_MEMORY_SCOPE_WORKGROUP) == 0 && \
           _n < (1 << 27)) { _n++; __builtin_amdgcn_s_sleep(1); } }

  double Pd1 = 0.0, Pd2 = 0.0;
  for (int p = 0; p < O_; p++) {
    Pd1 += (double)Mlds[p * O_ + lane];
    Pd2 += (double)Mlds[p * O_ + 64 + lane];
  }
  const float b1f = bias[lane], b2f = bias[lane + 64];
  int mk1 = 0, mk2 = 0;
  unsigned long long bmk1 = 0ull, bmk2 = 0ull;
  double ls_sum = 0.0;

  float g1c, g2c, g1n, g2n;
  WAITROW(0); g1c = Glds[lane];        g2c = Glds[64 + lane];
  WAITROW(1); g1n = Glds[O_ + lane];   g2n = Glds[O_ + 64 + lane];

  for (int j = 0; j < O_; j++) {
    if (snap && (j & 7) == 0) {           // state snapshot BEFORE step j
      int s = j >> 3;
      double2 pv; pv.x = Pd1; pv.y = Pd2;
      *(double2*)(snapPd + ((size_t)(b * 16 + s) * 64 + lane) * 2) = pv;
      if (lane == 0) {
        snapMk[(b * 16 + s) * 2 + 0] = bmk1;
        snapMk[(b * 16 + s) * 2 + 1] = bmk2;
      }
    }
    // exact reference op order (bit-identical to round-5 trajectory)
    float pm1 = mk1 ? NEGF : ((float)Pd1 + b1f);
    float pm2 = mk2 ? NEGF : ((float)Pd2 + b2f);
    float mx = wredmaxf(fmaxf(pm1, pm2));
    float s1 = pm1 - mx, s2 = pm2 - mx;
    float ss = wredsumf(expf(s1) + expf(s2));
    float lse = logf(ss);
    float lp1 = s1 - lse, lp2 = s2 - lse;
    float y1 = lp1 + g1c, y2 = lp2 + g2c;
    uint32_t u1 = mono32(y1), u2 = mono32(y2);
    uint32_t um = wredmaxu(u1 > u2 ? u1 : u2);
    unsigned long long bal1 = __ballot(u1 == um);
    unsigned long long bal2 = __ballot(u2 == um);
    int pos = bal1 ? (__ffsll(bal1) - 1) : (64 + __ffsll(bal2) - 1);

    // ls accumulation (off critical path)
    float lsel = rl_f((pos < 64) ? lp1 : lp2, pos & 63);
    ls_sum += (double)lsel;

    if (lane == 0) {
      posseq[b * O_ + j] = pos;
      out_pos[(size_t)b * O_ + (O_ - 1 - j)] = (float)pos;
    }
    mk1 |= (lane == pos);
    mk2 |= (lane + 64 == pos);
    if (pos < 64) bmk1 |= 1ull << pos; else bmk2 |= 1ull << (pos - 64);
    Pd1 -= (double)Mlds[pos * O_ + lane];
    Pd2 -= (double)Mlds[pos * O_ + 64 + lane];

    g1c = g1n; g2c = g2n;
    int r = j + 2;
    if (r < O_) {
      WAITROW(r);
      g1n = Glds[r * O_ + lane];
      g2n = Glds[r * O_ + 64 + lane];
    }
  }
#undef WAITROW
  if (lane == 0) out_ls[b] = (float)ls_sum;
}

// ---------------- Kernel E: rank/err per (b, 8-step chunk) ----------------
__global__ __launch_bounds__(64) void epilogue(
    const float* __restrict__ M, const float* __restrict__ bias,
    const int* __restrict__ posseq, const double* __restrict__ snapPd,
    const unsigned long long* __restrict__ snapMk, int snap,
    int* __restrict__ acc_err) {
  const int bid = blockIdx.x;
  const int b = bid >> 4, jc = bid & 15, j0 = jc * 8;
  const int lane = threadIdx.x;
  const float* Mb = M + (size_t)b * O_ * O_;

  const int pa = posseq[b * O_ + lane];
  const int pb = posseq[b * O_ + 64 + lane];

  double Pd1, Pd2;
  unsigned long long bmk1, bmk2;
  if (snap) {
    double2 pv = *(const double2*)(snapPd + ((size_t)(b * 16 + jc) * 64 + lane) * 2);
    Pd1 = pv.x; Pd2 = pv.y;
    bmk1 = snapMk[(b * 16 + jc) * 2 + 0];
    bmk2 = snapMk[(b * 16 + jc) * 2 + 1];
  } else {
    Pd1 = 0.0; Pd2 = 0.0;
    for (int p = 0; p < O_; p++) {
      Pd1 += (double)Mb[p * O_ + lane];
      Pd2 += (double)Mb[p * O_ + 64 + lane];
    }
    bmk1 = 0ull; bmk2 = 0ull;
    for (int i = 0; i < j0; i++) {
      int pos = __builtin_amdgcn_readlane(i < 64 ? pa : pb, i & 63);
      if (pos < 64) bmk1 |= 1ull << pos; else bmk2 |= 1ull << (pos - 64);
      Pd1 -= (double)Mb[pos * O_ + lane];
      Pd2 -= (double)Mb[pos * O_ + 64 + lane];
    }
  }
  const float b1f = bias[lane], b2f = bias[lane + 64];

  int err_acc = 0;
  for (int j = j0; j < j0 + 8; j++) {
    float p1 = (float)Pd1 + b1f;   // bit-identical to sampler's score
    float p2 = (float)Pd2 + b2f;
    // u64 keys: (mono<<7)|(127-idx): > means better rank, idx tie-break
    uint64_t K1 = ((uint64_t)mono32(p1) << 7) | (uint32_t)(127 - lane);
    uint64_t K2 = ((uint64_t)mono32(p2) << 7) | (uint32_t)(63 - lane);
    int c1 = 0, c2 = 0;
#pragma unroll 8
    for (int q = 0; q < 64; q++) {
      uint64_t s1 = rl_u64(K1, q), s2 = rl_u64(K2, q);
      c1 += (s1 > K1) ? 1 : 0;
      c1 += (s2 > K1) ? 1 : 0;
      c2 += (s1 > K2) ? 1 : 0;
      c2 += (s2 > K2) ? 1 : 0;
    }
    unsigned long long t1 = __ballot(c1 == j), t2 = __ballot(c2 == j);
    int topl, msk;
    if (t1) { topl = __ffsll(t1) - 1; msk = (int)((bmk1 >> topl) & 1); }
    else    { topl = __ffsll(t2) - 1; msk = (int)((bmk2 >> topl) & 1); }
    err_acc += msk;

    int pos = __builtin_amdgcn_readlane(j < 64 ? pa : pb, j & 63);
    if (pos < 64) bmk1 |= 1ull << pos; else bmk2 |= 1ull << (pos - 64);
    Pd1 -= (double)Mb[pos * O_ + lane];
    Pd2 -= (double)Mb[pos * O_ + 64 + lane];
  }
  if (lane == 0) atomicAdd(&acc_err[b], err_acc);
}

// ---------------- Kernel P: pack err to output ----------------
__global__ __launch_bounds__(256) void pack_out(
    const int* __restrict__ acc_err, float* __restrict__ out_err) {
  int t = threadIdx.x;
  out_err[t] = (float)acc_err[t];
}

extern "C" void kernel_launch(void* const* d_in, const int* in_sizes, int n_in,
                              void* d_out, int out_size, void* d_ws, size_t ws_size,
                              hipStream_t stream) {
  const float* enc  = (const float*)d_in[0];
  const float* W    = (const float*)d_in[1];
  const float* bias = (const float*)d_in[2];
  float* out     = (float*)d_out;
  float* out_pos = out;                  // [256][128] positions (as f32)
  float* out_ls  = out + B_ * O_;        // [256]
  float* out_err = out + B_ * O_ + B_;   // [256]

  char* ws = (char*)d_ws;
  int* posseq  = (int*)ws;                                   // 131072 B
  int* acc_err = (int*)(ws + 131072);                        // 1024 B
  unsigned long long* snapMk = (unsigned long long*)(ws + 132096);  // 65536 B
  double* snapPd = (double*)(ws + 197632);                   // 4 MB
  const size_t snap_need = 4391936 + (size_t)B_ * O_ * O_ * 4;  // ~21.2 MB
  int snap = (ws_size >= snap_need) ? 1 : 0;
  float* M = (float*)(ws + (snap ? 4391936 : 132096));

  build_M<<<dim3(O_, 2), 256, 0, stream>>>(enc, W, M, acc_err);
  sampler<<<dim3(B_), 256, 0, stream>>>(M, bias, out_pos, out_ls,
                                        posseq, snapPd, snapMk, snap);
  epilogue<<<dim3(B_ * 16), 64, 0, stream>>>(M, bias, posseq, snapPd, snapMk,
                                             snap, acc_err);
  pack_out<<<dim3(1), 256, 0, stream>>>(acc_err, out_err);
}

// Round 7
// 210.487 us; speedup vs baseline: 2.6695x; 1.1294x over previous
//
#include <hip/hip_runtime.h>
#include <stdint.h>

#define B_   256
#define O_   128
#define D_   128
#define IN_  16384
#define NEGF (-9.0e15f)
#define TINYF 1.1754943508222875e-38f
#define WGSCOPE __HIP_MEMORY_SCOPE_WORKGROUP

// ---------------- threefry2x32 (JAX partitionable, 20 rounds) ----------------
__device__ __forceinline__ void tf2x32(uint32_t k0, uint32_t k1,
                                       uint32_t x0, uint32_t x1,
                                       uint32_t* o0, uint32_t* o1) {
  uint32_t k2 = k0 ^ k1 ^ 0x1BD11BDAu;
#define TFR(r) { x0 += x1; x1 = (x1 << (r)) | (x1 >> (32 - (r))); x1 ^= x0; }
  x0 += k0; x1 += k1;
  TFR(13) TFR(15) TFR(26) TFR(6)
  x0 += k1; x1 += k2 + 1u;
  TFR(17) TFR(29) TFR(16) TFR(24)
  x0 += k2; x1 += k0 + 2u;
  TFR(13) TFR(15) TFR(26) TFR(6)
  x0 += k0; x1 += k1 + 3u;
  TFR(17) TFR(29) TFR(16) TFR(24)
  x0 += k1; x1 += k2 + 4u;
  TFR(13) TFR(15) TFR(26) TFR(6)
  x0 += k2; x1 += k0 + 5u;
#undef TFR
  *o0 = x0; *o1 = x1;
}

__device__ __forceinline__ float gumbel_bits(uint32_t bits) {
  float f = __uint_as_float((bits >> 9) | 0x3f800000u) - 1.0f;  // [0,1)
  float u = fmaxf(TINYF, f + TINYF);
  return -logf(-logf(u));
}

__device__ __forceinline__ uint32_t mono32(float x) {
  int b = __float_as_int(x);
  return (uint32_t)b ^ ((uint32_t)(b >> 31) | 0x80000000u);
}

__device__ __forceinline__ float rl_f(float v, int l) {
  return __int_as_float(__builtin_amdgcn_readlane(__float_as_int(v), l));
}
__device__ __forceinline__ uint32_t rl_u(uint32_t v, int l) {
  return (uint32_t)__builtin_amdgcn_readlane((int)v, l);
}
__device__ __forceinline__ uint64_t rl_u64(uint64_t v, int l) {
  uint32_t lo = (uint32_t)__builtin_amdgcn_readlane((int)(uint32_t)v, l);
  uint32_t hi = (uint32_t)__builtin_amdgcn_readlane((int)(uint32_t)(v >> 32), l);
  return ((uint64_t)hi << 32) | lo;
}

// DPP helpers. Reduction: xor1,2,4,8 butterfly within rows of 16, then
// row_bcast15 + row_bcast31 funnel into lane 63. Sum result is bitwise equal
// to the old (r0+r1)+(r2+r3) tail (only commutative swaps of identical adds).
#define DPPF(x, ctrl) __int_as_float(__builtin_amdgcn_mov_dpp( \
    __float_as_int(x), (ctrl), 0xf, 0xf, true))
#define DPPU(x, ctrl) ((uint32_t)__builtin_amdgcn_mov_dpp( \
    (int)(x), (ctrl), 0xf, 0xf, true))

__device__ __forceinline__ float wredmaxf(float x) {
  x = fmaxf(x, DPPF(x, 0xB1));
  x = fmaxf(x, DPPF(x, 0x4E));
  x = fmaxf(x, DPPF(x, 0x141));
  x = fmaxf(x, DPPF(x, 0x140));
  x = fmaxf(x, DPPF(x, 0x142));   // row_bcast15
  x = fmaxf(x, DPPF(x, 0x143));   // row_bcast31
  return rl_f(x, 63);
}
__device__ __forceinline__ float wredsumf(float x) {
  x = x + DPPF(x, 0xB1);
  x = x + DPPF(x, 0x4E);
  x = x + DPPF(x, 0x141);
  x = x + DPPF(x, 0x140);
  x = x + DPPF(x, 0x142);
  x = x + DPPF(x, 0x143);
  return rl_f(x, 63);
}
__device__ __forceinline__ uint32_t wredmaxu(uint32_t x) {
  uint32_t y;
  y = DPPU(x, 0xB1);  x = x > y ? x : y;
  y = DPPU(x, 0x4E);  x = x > y ? x : y;
  y = DPPU(x, 0x141); x = x > y ? x : y;
  y = DPPU(x, 0x140); x = x > y ? x : y;
  y = DPPU(x, 0x142); x = x > y ? x : y;
  y = DPPU(x, 0x143); x = x > y ? x : y;
  return rl_u(x, 63);
}

// ---------------- Kernel A: M[b][p][o] = <enc[b,p,:], W[o, p*D:(p+1)*D]> ----
// grid = (128 p, 2 b-halves), 256 threads. Coalesced staging: half-wave per row.
__global__ __launch_bounds__(256, 1) void build_M(
    const float* __restrict__ enc, const float* __restrict__ W,
    float* __restrict__ M) {
  const int p  = blockIdx.x;
  const int b0 = blockIdx.y * 128;
  const int t  = threadIdx.x;

  __shared__ float Ws[128 * 132];
  __shared__ float Es[128 * 132];

  {
    const int rgrp = t >> 5;      // 8 rows per iteration
    const int c16  = t & 31;      // float4 index within a 512B row
#pragma unroll
    for (int k = 0; k < 16; k++) {
      int row = k * 8 + rgrp;
      *(float4*)(Ws + row * 132 + c16 * 4) =
          *(const float4*)(W + (size_t)row * IN_ + p * D_ + c16 * 4);
    }
#pragma unroll
    for (int k = 0; k < 16; k++) {
      int row = k * 8 + rgrp;
      *(float4*)(Es + row * 132 + c16 * 4) =
          *(const float4*)(enc + ((size_t)(b0 + row) * O_ + p) * D_ + c16 * 4);
    }
  }
  __syncthreads();

  const int og = t & 15, bg = t >> 4;
  float acc0[8][8] = {}, acc1[8][8] = {};

  for (int dc = 0; dc < 128; dc += 4) {
    float4 wv[8], ev[8];
#pragma unroll
    for (int oi = 0; oi < 8; oi++)
      wv[oi] = *(const float4*)(Ws + (og + 16 * oi) * 132 + dc);
#pragma unroll
    for (int bi = 0; bi < 8; bi++)
      ev[bi] = *(const float4*)(Es + (bg + 16 * bi) * 132 + dc);
#pragma unroll
    for (int bi = 0; bi < 8; bi++)
#pragma unroll
      for (int oi = 0; oi < 8; oi++) {
        acc0[bi][oi] += ev[bi].x * wv[oi].x;
        acc1[bi][oi] += ev[bi].y * wv[oi].y;
        acc0[bi][oi] += ev[bi].z * wv[oi].z;
        acc1[bi][oi] += ev[bi].w * wv[oi].w;
      }
  }
#pragma unroll
  for (int bi = 0; bi < 8; bi++) {
    int b = b0 + bg + 16 * bi;
#pragma unroll
    for (int oi = 0; oi < 8; oi++) {
      int o = og + 16 * oi;
      M[((size_t)b * O_ + p) * O_ + o] = acc0[bi][oi] + acc1[bi][oi];
    }
  }
}

// ---------------- Kernel S: fused sampler + producers + rank workers --------
// 512 threads: wave0 = serial sampler; waves1-3 = gumbel producers then rank
// workers; waves4-7 = rank workers. All rank/err work consumes LDS snapshots.
__global__ __launch_bounds__(512, 1) void sampler(
    const float* __restrict__ M, const float* __restrict__ bias,
    const float* __restrict__ enc, const float* __restrict__ W, int use_M,
    float* __restrict__ out_pos, float* __restrict__ out_ls,
    float* __restrict__ out_err) {
  const int b = blockIdx.x;
  const int t = threadIdx.x;
  const int lane = t & 63;
  const int w = t >> 6;

  __shared__ float  Mlds[O_ * O_];          // 64 KB
  __shared__ float  Gring[32 * O_];         // 16 KB (32-row gumbel ring)
  __shared__ double snapPd[16 * 64 * 2];    // 16 KB (per-chunk Pd snapshot)
  __shared__ unsigned long long snapMk[16 * 2];
  __shared__ int posb[O_];
  __shared__ int flags[O_];
  __shared__ int doneStep, errTot, chunksDone;

  if (use_M) {
    const float4* src = (const float4*)(M + (size_t)b * O_ * O_);
    for (int i = t; i < O_ * O_ / 4; i += 512) ((float4*)Mlds)[i] = src[i];
  } else {
    for (int idx = t; idx < O_ * O_; idx += 512) {
      int p = idx >> 7, o = idx & 127;
      const float* er = enc + ((size_t)b * O_ + p) * D_;
      const float* wr = W + (size_t)o * IN_ + p * D_;
      float s = 0.f;
      for (int d = 0; d < D_; d += 4) {
        float4 e4 = *(const float4*)(er + d);
        float4 w4 = *(const float4*)(wr + d);
        s += e4.x * w4.x + e4.y * w4.y + e4.z * w4.z + e4.w * w4.w;
      }
      Mlds[idx] = s;
    }
  }
  if (t < O_) flags[t] = 0;
  if (t == 0) { doneStep = 0; errTot = 0; chunksDone = 0; }
  __syncthreads();

  if (w >= 1 && w <= 3) {
    // ---- producers: rows r == (w-1) mod 3, into 32-row ring ----
    for (int r = w - 1; r < O_; r += 3) {
      if (r >= 32) {   // don't overwrite a ring slot the consumer hasn't passed
        int n = 0;
        while (__hip_atomic_load(&doneStep, __ATOMIC_ACQUIRE, WGSCOPE) < r - 30 &&
               n < (1 << 26)) { n++; __builtin_amdgcn_s_sleep(8); }
      }
      uint32_t k0j, k1j, w0, w1;
      tf2x32(0u, 42u, 0u, (uint32_t)r, &k0j, &k1j);
      uint32_t m1 = (uint32_t)(b * O_ + lane);
      tf2x32(k0j, k1j, 0u, m1, &w0, &w1);
      float g1 = gumbel_bits(w0 ^ w1);
      tf2x32(k0j, k1j, 0u, m1 + 64u, &w0, &w1);
      float g2 = gumbel_bits(w0 ^ w1);
      Gring[(r & 31) * O_ + lane] = g1;
      Gring[(r & 31) * O_ + 64 + lane] = g2;
      if (lane == 0)
        __hip_atomic_store(&flags[r], 1, __ATOMIC_RELEASE, WGSCOPE);
    }
  }

  if (w == 0) {
    // ---- consumer: the serial decision chain ----
    __builtin_amdgcn_s_setprio(3);
#define WAITF(r) { int _n = 0; \
    while (__hip_atomic_load(&flags[r], __ATOMIC_ACQUIRE, WGSCOPE) == 0 && \
           _n < (1 << 26)) { _n++; __builtin_amdgcn_s_sleep(1); } }
    double Pd1 = 0.0, Pd2 = 0.0;
    for (int p = 0; p < O_; p++) {
      Pd1 += (double)Mlds[p * O_ + lane];
      Pd2 += (double)Mlds[p * O_ + 64 + lane];
    }
    const float b1f = bias[lane], b2f = bias[lane + 64];
    int mk1 = 0, mk2 = 0;
    unsigned long long bmk1 = 0ull, bmk2 = 0ull;
    double ls_sum = 0.0;

    WAITF(7); WAITF(8); WAITF(9);    // producers in-order => rows 0..9 ready
    float g1c = Gring[lane],      g2c = Gring[64 + lane];
    float g1n = Gring[O_ + lane], g2n = Gring[O_ + 64 + lane];

    for (int j = 0; j < O_; j++) {
      if ((j & 7) == 0) {
        if (j) {  // rows j+2..j+9 needed this group; 3 consecutive flags cover
          int rA = j + 7, rB = j + 8, rC = j + 9;
          if (rC > 127) { rA = 125; rB = 126; rC = 127; }
          WAITF(rA); WAITF(rB); WAITF(rC);
        }
        int c = j >> 3;   // snapshot state entering step 8c
        double2 pv; pv.x = Pd1; pv.y = Pd2;
        *(double2*)&snapPd[(c * 64 + lane) * 2] = pv;
        if (lane == 0) { snapMk[c * 2] = bmk1; snapMk[c * 2 + 1] = bmk2; }
      }
      // exact reference op order (bit-identical to round-5/6 trajectory)
      float pm1 = mk1 ? NEGF : ((float)Pd1 + b1f);
      float pm2 = mk2 ? NEGF : ((float)Pd2 + b2f);
      float mx = wredmaxf(fmaxf(pm1, pm2));
      float s1 = pm1 - mx, s2 = pm2 - mx;
      float ss = wredsumf(expf(s1) + expf(s2));
      float lse = logf(ss);
      float lp1 = s1 - lse, lp2 = s2 - lse;
      float y1 = lp1 + g1c, y2 = lp2 + g2c;
      uint32_t u1 = mono32(y1), u2 = mono32(y2);
      uint32_t um = wredmaxu(u1 > u2 ? u1 : u2);
      unsigned long long bal1 = __ballot(u1 == um);
      unsigned long long bal2 = __ballot(u2 == um);
      int pos = bal1 ? (__ffsll(bal1) - 1) : (64 + __ffsll(bal2) - 1);

      float lsel = rl_f((pos < 64) ? lp1 : lp2, pos & 63);
      ls_sum += (double)lsel;

      if (lane == 0) {
        posb[j] = pos;
        out_pos[(size_t)b * O_ + (O_ - 1 - j)] = (float)pos;
      }
      mk1 |= (lane == pos);
      mk2 |= (lane + 64 == pos);
      if (pos < 64) bmk1 |= 1ull << pos; else bmk2 |= 1ull << (pos - 64);
      Pd1 -= (double)Mlds[pos * O_ + lane];
      Pd2 -= (double)Mlds[pos * O_ + 64 + lane];
      if (lane == 0)
        __hip_atomic_store(&doneStep, j + 1, __ATOMIC_RELEASE, WGSCOPE);

      g1c = g1n; g2c = g2n;
      int r = j + 2;
      if (r < O_) {
        g1n = Gring[(r & 31) * O_ + lane];
        g2n = Gring[(r & 31) * O_ + 64 + lane];
      }
    }
#undef WAITF
    if (lane == 0) out_ls[b] = (float)ls_sum;
  }

  if (w >= 1) {
    // ---- rank/err workers: chunk c handled by wave 1 + (c % 7) ----
    const float b1f = bias[lane], b2f = bias[lane + 64];
    for (int c = w - 1; c < 16; c += 7) {
      int need = 8 * c + 8, n = 0;
      while (__hip_atomic_load(&doneStep, __ATOMIC_ACQUIRE, WGSCOPE) < need &&
             n < (1 << 26)) { n++; __builtin_amdgcn_s_sleep(8); }
      double2 pv = *(double2*)&snapPd[(c * 64 + lane) * 2];
      double Pd1 = pv.x, Pd2 = pv.y;
      unsigned long long bmk1 = snapMk[c * 2], bmk2 = snapMk[c * 2 + 1];
      int err_acc = 0;
      for (int j = 8 * c; j < 8 * c + 8; j++) {
        float p1 = (float)Pd1 + b1f;   // bit-identical to sampler's score
        float p2 = (float)Pd2 + b2f;
        uint64_t K1 = ((uint64_t)mono32(p1) << 7) | (uint32_t)(127 - lane);
        uint64_t K2 = ((uint64_t)mono32(p2) << 7) | (uint32_t)(63 - lane);
        int c1 = 0, c2 = 0;
#pragma unroll 8
        for (int q = 0; q < 64; q++) {
          uint64_t s1v = rl_u64(K1, q), s2v = rl_u64(K2, q);
          c1 += (s1v > K1) ? 1 : 0;
          c1 += (s2v > K1) ? 1 : 0;
          c2 += (s1v > K2) ? 1 : 0;
          c2 += (s2v > K2) ? 1 : 0;
        }
        unsigned long long t1 = __ballot(c1 == j), t2 = __ballot(c2 == j);
        int topl, msk;
        if (t1) { topl = __ffsll(t1) - 1; msk = (int)((bmk1 >> topl) & 1); }
        else    { topl = __ffsll(t2) - 1; msk = (int)((bmk2 >> topl) & 1); }
        err_acc += msk;

        int pos = posb[j];
        if (pos < 64) bmk1 |= 1ull << pos; else bmk2 |= 1ull << (pos - 64);
        Pd1 -= (double)Mlds[pos * O_ + lane];
        Pd2 -= (double)Mlds[pos * O_ + 64 + lane];
      }
      if (lane == 0) {
        __hip_atomic_fetch_add(&errTot, err_acc, __ATOMIC_RELAXED, WGSCOPE);
        int prev = __hip_atomic_fetch_add(&chunksDone, 1, __ATOMIC_ACQ_REL,
                                          WGSCOPE);
        if (prev == 15)
          out_err[b] = (float)__hip_atomic_load(&errTot, __ATOMIC_ACQUIRE,
                                                WGSCOPE);
      }
    }
  }
}

extern "C" void kernel_launch(void* const* d_in, const int* in_sizes, int n_in,
                              void* d_out, int out_size, void* d_ws, size_t ws_size,
                              hipStream_t stream) {
  const float* enc  = (const float*)d_in[0];
  const float* W    = (const float*)d_in[1];
  const float* bias = (const float*)d_in[2];
  float* out     = (float*)d_out;
  float* out_pos = out;                  // [256][128] positions (as f32)
  float* out_ls  = out + B_ * O_;        // [256]
  float* out_err = out + B_ * O_ + B_;   // [256]

  float* M = (float*)d_ws;
  const size_t needM = (size_t)B_ * O_ * O_ * sizeof(float);  // 16.7 MB
  int use_M = (ws_size >= needM) ? 1 : 0;

  if (use_M) build_M<<<dim3(O_, 2), 256, 0, stream>>>(enc, W, M);
  sampler<<<dim3(B_), 512, 0, stream>>>(M, bias, enc, W, use_M,
                                        out_pos, out_ls, out_err);
}